// Round 1
// baseline (777.253 us; speedup 1.0000x reference)
//
#include <hip/hip_runtime.h>

#define NB 8
#define TQv 2048
#define TKv 2048
#define FD 1024
#define HD 1024

typedef __attribute__((ext_vector_type(8))) short short8;
typedef __attribute__((ext_vector_type(8))) _Float16 half8;
typedef __attribute__((ext_vector_type(4))) float f32x4;

// round-to-nearest-even fp32 -> bf16 (finite inputs only)
__device__ __forceinline__ short f2bf(float f) {
    union { float f; unsigned u; } v; v.f = f;
    unsigned r = v.u + 0x7FFFu + ((v.u >> 16) & 1u);
    return (short)(r >> 16);
}

__device__ __forceinline__ half8 as_h8(short8 v) {
    union { short8 s; half8 h; } u; u.s = v; return u.h;
}

// async 16B global -> LDS (global_load_lds_dwordx4); LDS dest = wave-uniform base + lane*16
__device__ __forceinline__ void async16(const short* g, short* l) {
    __builtin_amdgcn_global_load_lds(
        (const __attribute__((address_space(1))) unsigned int*)g,
        (__attribute__((address_space(3))) unsigned int*)l, 16, 0, 0);
}

#define BAR  __builtin_amdgcn_s_barrier()
#define SP1  __builtin_amdgcn_s_setprio(1)
#define SP0  __builtin_amdgcn_s_setprio(0)
#define VMCNT(N) asm volatile("s_waitcnt vmcnt(" #N ")" ::: "memory")
// rule #18: sched_barrier(0) right after an inline-asm lgkmcnt so MFMA can't hoist past it
#define LGK0 do { asm volatile("s_waitcnt lgkmcnt(0)" ::: "memory"); \
                  __builtin_amdgcn_sched_barrier(0); } while (0)

// ===================== 256x256 8-phase GEMM core (T2+T3+T4+T5) =====================
// NT form: C[m][n] = sum_k A[m][k]*B[n][k].  512 threads = 8 waves (2M x 4N);
// per-wave C = 128x64 = acc[8][4] f32x4 frags, 16x16x32 MFMA, BK=64, K-tiles double-buffered.
// LDS 128 KiB: buf{0,1} x { A: 2 halves of [128 rows][64 k], B: same } bf16.
//   XOR swizzle: element (row,k) of a half lives in 16B block L = 8*row + ((k>>3)^(row&7)).
//   Staging is LINEAR in L (global_load_lds constraint); the global source is pre-swizzled:
//   block L -> src row = L>>3, chunk = (L&7)^(row&7)  => per 8 rows: 8 coalesced 16B/lane runs.
//   Fragment read (16 rows, fixed chunk): banks 4*((chunk)^(r&7)) sweep all 32 per 8 rows.
// Phase schedule per iter (tile a=2*it -> buf0, b=a+1 -> buf1), 16 MFMA per phase:
//   P1 rd A(q0)+B(q0) buf0   stg B0(b)     | P5 rd A(q0)+B(q0) buf1   stg B0(a+2)
//   P2 rd A(q1)       buf0   stg B1(b)     | P6 rd A(q1)       buf1   stg B1(a+2)
//   P3 rd B(q1)       buf0   stg A0(a+2)   | P7 rd B(q1)       buf1   stg A0(a+3)
//   P4 (no rd)               stg A1(a+2)   | P8 (no rd)               stg A1(a+3)
//                            VMCNT(4)      |                          VMCNT(4)
// vmcnt ledger (half-tiles = 2 loads each): outstanding at P4/P8 wait = 6 ht; drain to
// 2 ht => all 4 ht of the tile computed in the NEXT 4 phases have landed (incl. B(b)
// staged at P1/P2, A(b) staged at P7/P8 of prev iter).  WAR safety: every stage targets
// an LDS region whose last ds_read was in an earlier, barrier-separated phase
// (A halves last read P2/P6, B halves last read P3/P7).
// Never __syncthreads() in the loop (it drains vmcnt(0) and kills the pipeline).

#define STG_A(BF, H, T) { async16(gA[H][0] + (T)*64, lA[BF][H][0]); \
                          async16(gA[H][1] + (T)*64, lA[BF][H][1]); }
#define STG_B(BF, H, T) { async16(gB[H][0] + (T)*64, lB[BF][H][0]); \
                          async16(gB[H][1] + (T)*64, lB[BF][H][1]); }

#define RD_A(dst, BF, QM) { _Pragma("unroll") for (int ml = 0; ml < 4; ++ml) { \
    dst[ml][0] = *(const short8*)(rdA + (BF)*65536 + ((QM)*64 + ml*16)*128 + o0); \
    dst[ml][1] = *(const short8*)(rdA + (BF)*65536 + ((QM)*64 + ml*16)*128 + o1); } }
#define RD_B(dst, BF, QN) { _Pragma("unroll") for (int nq = 0; nq < 2; ++nq) { \
    dst[nq][0] = *(const short8*)(rdB + (BF)*65536 + ((QN)*32 + nq*16)*128 + o0); \
    dst[nq][1] = *(const short8*)(rdB + (BF)*65536 + ((QN)*32 + nq*16)*128 + o1); } }

#define DO_MFMA(AF, BFR, QM, QN) { \
    _Pragma("unroll") for (int ks = 0; ks < 2; ++ks) \
    _Pragma("unroll") for (int ml = 0; ml < 4; ++ml) \
    _Pragma("unroll") for (int nq = 0; nq < 2; ++nq) { \
        if constexpr (F16) \
            acc[(QM)*4 + ml][(QN)*2 + nq] = __builtin_amdgcn_mfma_f32_16x16x32_f16( \
                as_h8(AF[ml][ks]), as_h8(BFR[nq][ks]), acc[(QM)*4 + ml][(QN)*2 + nq], 0, 0, 0); \
        else \
            acc[(QM)*4 + ml][(QN)*2 + nq] = __builtin_amdgcn_mfma_f32_16x16x32_bf16( \
                AF[ml][ks], BFR[nq][ks], acc[(QM)*4 + ml][(QN)*2 + nq], 0, 0, 0); } }

template <bool F16>
__device__ __forceinline__ void gemm256_core(const short* __restrict__ A,
                                             const short* __restrict__ B,
                                             int ldK, int K, char* smem,
                                             f32x4 acc[8][4], int tid) {
    const int wid = tid >> 6, lane = tid & 63;
    const int wm = wid >> 2, wn = wid & 3;

    // ---- staging setup: thread covers swizzled blocks {tid, tid+512} of each half-tile ----
    const int lr  = wid * 8 + (lane >> 3);              // source row (within 64-row j-window)
    const int kc8 = ((lane & 7) ^ (lane >> 3)) * 8;     // pre-swizzled source k-chunk
    const short* gA[2][2]; const short* gB[2][2];       // [half][j]
    short* lA[2][2][2]; short* lB[2][2][2];             // [buf][half][j]
#pragma unroll
    for (int h = 0; h < 2; ++h)
#pragma unroll
        for (int j = 0; j < 2; ++j) {
            gA[h][j] = A + (size_t)(h * 128 + j * 64 + lr) * ldK + kc8;
            gB[h][j] = B + (size_t)(h * 128 + j * 64 + lr) * ldK + kc8;
#pragma unroll
            for (int bf = 0; bf < 2; ++bf) {
                lA[bf][h][j] = (short*)(smem + bf * 65536 +         h * 16384 + (j * 512 + wid * 64) * 16);
                lB[bf][h][j] = (short*)(smem + bf * 65536 + 32768 + h * 16384 + (j * 512 + wid * 64) * 16);
            }
        }

    // ---- fragment-read setup: A rows from half wm, B rows from half (wn>>1) ----
    const int l15 = lane & 15;
    const int o0 = (((lane >> 4)    ) ^ (lane & 7)) * 16;   // ks=0 swizzled chunk offset
    const int o1 = (((lane >> 4) + 4) ^ (lane & 7)) * 16;   // ks=1
    char* rdA = smem + wm * 16384 + l15 * 128;
    char* rdB = smem + 32768 + (wn >> 1) * 16384 + (wn & 1) * 8192 + l15 * 128;

    // ---- prologue: buf0 full tile0 + buf1 A-halves of tile1; drain buf0 ----
    STG_A(0, 0, 0); STG_A(0, 1, 0); STG_B(0, 0, 0); STG_B(0, 1, 0);
    STG_A(1, 0, 1); STG_A(1, 1, 1);
    VMCNT(4);     // 12 issued, keep last 4 loads (=A(t1)) outstanding -> tile0 landed
    BAR;

    const int nt = K >> 6;
    const int niter = nt >> 1;
    short8 a0[4][2], a1[4][2], b0[2][2], b1[2][2];
    for (int it = 0; it < niter; ++it) {
        const int a = it * 2;
        const bool nolast = (it != niter - 1);
        // P1
        RD_A(a0, 0, 0); RD_B(b0, 0, 0);
        STG_B(1, 0, a + 1);
        BAR; LGK0; SP1; DO_MFMA(a0, b0, 0, 0); SP0; BAR;
        // P2
        RD_A(a1, 0, 1);
        STG_B(1, 1, a + 1);
        BAR; LGK0; SP1; DO_MFMA(a1, b0, 1, 0); SP0; BAR;
        // P3
        RD_B(b1, 0, 1);
        if (nolast) STG_A(0, 0, a + 2);
        BAR; LGK0; SP1; DO_MFMA(a0, b1, 0, 1); SP0; BAR;
        // P4
        if (nolast) { STG_A(0, 1, a + 2); VMCNT(4); } else { VMCNT(0); }
        BAR; SP1; DO_MFMA(a1, b1, 1, 1); SP0; BAR;
        // P5
        RD_A(a0, 1, 0); RD_B(b0, 1, 0);
        if (nolast) STG_B(0, 0, a + 2);
        BAR; LGK0; SP1; DO_MFMA(a0, b0, 0, 0); SP0; BAR;
        // P6
        RD_A(a1, 1, 1);
        if (nolast) STG_B(0, 1, a + 2);
        BAR; LGK0; SP1; DO_MFMA(a1, b0, 1, 0); SP0; BAR;
        // P7
        RD_B(b1, 1, 1);
        if (nolast) STG_A(1, 0, a + 3);
        BAR; LGK0; SP1; DO_MFMA(a0, b1, 0, 1); SP0; BAR;
        // P8
        if (nolast) { STG_A(1, 1, a + 3); VMCNT(4); }
        BAR; SP1; DO_MFMA(a1, b1, 1, 1); SP0; BAR;
    }
}

// C/D layout per 16x16x32 frag (m89/m91): col = lane&15, row = 4*(lane>>4) + r
// global: row = tile_m + wm*128 + m*16 + 4*(lane>>4) + r ; col = tile_n + wn*64 + n*16 + (lane&15)

// ---- fp32 -> bf16 pre-pass for query & encoder_states ----
__global__ __launch_bounds__(256) void convert_kernel(const float* __restrict__ q,
                                                      const float* __restrict__ e,
                                                      short* __restrict__ xq,
                                                      short* __restrict__ xe) {
    size_t i = (size_t)blockIdx.x * 256 + threadIdx.x;
    const float* src = blockIdx.y ? e : q;
    short* dst = blockIdx.y ? xe : xq;
    float4 a = ((const float4*)src)[2 * i];
    float4 b = ((const float4*)src)[2 * i + 1];
    short8 v;
    v[0] = f2bf(a.x); v[1] = f2bf(a.y); v[2] = f2bf(a.z); v[3] = f2bf(a.w);
    v[4] = f2bf(b.x); v[5] = f2bf(b.y); v[6] = f2bf(b.z); v[7] = f2bf(b.w);
    ((short8*)dst)[i] = v;
}

// ---- W[F][H] fp32 -> Wt[H][F] bf16, z picks Wq/Wk/Wv ----
__global__ __launch_bounds__(256) void wtrans_kernel(const float* __restrict__ Wq,
                                                     const float* __restrict__ Wk,
                                                     const float* __restrict__ Wv,
                                                     short* __restrict__ Wt) {
    __shared__ float tile[32][33];
    const float* W = (blockIdx.z == 0) ? Wq : (blockIdx.z == 1) ? Wk : Wv;
    short* dst = Wt + (size_t)blockIdx.z * HD * FD;
    int h0 = blockIdx.x * 32, f0 = blockIdx.y * 32;
    int tx = threadIdx.x, ty = threadIdx.y;
    for (int j = ty; j < 32; j += 8)
        tile[j][tx] = W[(size_t)(f0 + j) * HD + h0 + tx];
    __syncthreads();
    for (int j = ty; j < 32; j += 8)
        dst[(size_t)(h0 + j) * FD + f0 + tx] = f2bf(tile[tx][j]);
}

// ---- Q/K projections: 256x256 tiles over [16384 x 1024] ----
__global__ __launch_bounds__(512, 2) void projqk_kernel(const short* __restrict__ Xq,
                                                        const short* __restrict__ Xe,
                                                        const short* __restrict__ Wt3,
                                                        const float* __restrict__ bq,
                                                        const float* __restrict__ bk,
                                                        short* __restrict__ Q,
                                                        short* __restrict__ K) {
    extern __shared__ char smem[];
    int tid = threadIdx.x;
    int p = blockIdx.z;
    const short* X = p ? Xe : Xq;
    const short* Wt = Wt3 + (size_t)p * HD * FD;
    const float* bias = p ? bk : bq;
    short* O = p ? K : Q;
    int bid = blockIdx.x;                   // XCD swizzle: m-groups bound to XCDs
    int xcd = bid & 7, idx = bid >> 3;
    int n_t = idx & 3, m_t = (idx >> 2) * 8 + xcd;
    int tile_m = m_t * 256, tile_n = n_t * 256;
    f32x4 acc[8][4] = {};
    gemm256_core<false>(X + (size_t)tile_m * FD, Wt + (size_t)tile_n * FD, FD, FD, smem, acc, tid);
    int wid = tid >> 6, lane = tid & 63;
    int wm = wid >> 2, wn = wid & 3;
    int row0 = tile_m + wm * 128 + ((lane >> 4) << 2);
    int col0 = tile_n + wn * 64 + (lane & 15);
#pragma unroll
    for (int n = 0; n < 4; ++n) {
        int gn = col0 + n * 16;
        float bv_ = bias[gn];
#pragma unroll
        for (int m = 0; m < 8; ++m)
#pragma unroll
            for (int r = 0; r < 4; ++r)
                O[(size_t)(row0 + m * 16 + r) * HD + gn] = f2bf(acc[m][n][r] + bv_);
    }
}

// ---- V projection, transposed natively: Vt[b][h][t] = Wtv[h,:].Xe[b,t,:] + bv[h], fp16 out ----
__global__ __launch_bounds__(512, 2) void projv_kernel(const short* __restrict__ Xe,
                                                       const short* __restrict__ Wtv,
                                                       const float* __restrict__ bv,
                                                       short* __restrict__ Vt) {
    extern __shared__ char smem[];
    int tid = threadIdx.x;
    int bid = blockIdx.x;
    int b = bid & 7, i = bid >> 3;          // batch -> XCD binding
    int m_t = i & 3, n_t = i >> 2;          // m over HD (4), n over TKv (8)
    int tile_m = m_t * 256, tile_n = n_t * 256;
    const short* Xb = Xe + (size_t)b * TKv * FD;
    f32x4 acc[8][4] = {};
    gemm256_core<false>(Wtv + (size_t)tile_m * FD, Xb + (size_t)tile_n * FD, FD, FD, smem, acc, tid);
    short* Ob = Vt + (size_t)b * HD * TKv;
    int wid = tid >> 6, lane = tid & 63;
    int wm = wid >> 2, wn = wid & 3;
    int row0 = tile_m + wm * 128 + ((lane >> 4) << 2);
    int col0 = tile_n + wn * 64 + (lane & 15);
#pragma unroll
    for (int m = 0; m < 8; ++m)
#pragma unroll
        for (int r = 0; r < 4; ++r) {
            int gm = row0 + m * 16 + r;     // h
            float bv_ = bv[gm];
#pragma unroll
            for (int n = 0; n < 4; ++n) {
                union { _Float16 h; short s; } cv;
                cv.h = (_Float16)(acc[m][n][r] + bv_);
                Ob[(size_t)gm * TKv + col0 + n * 16] = cv.s;
            }
        }
}

// ---- mask int32 -> bitmask u64 (ballot), + zero row-sum array L ----
__global__ __launch_bounds__(256) void maskbits_kernel(const int* __restrict__ mask,
                                                       unsigned long long* __restrict__ Mbits,
                                                       float* __restrict__ L) {
    int tid = threadIdx.x;
    int lane = tid & 63;
    if (blockIdx.x < 64) L[blockIdx.x * 256 + tid] = 0.f;
    const int NW = NB * TQv * (TKv / 64);
    int stride = gridDim.x * 4;
    for (int w = blockIdx.x * 4 + (tid >> 6); w < NW; w += stride) {
        int v = mask[(size_t)w * 64 + lane];
        unsigned long long bal = __ballot(v != 0);
        if (lane == 0) Mbits[w] = bal;
    }
}

// ---- score: P' = mask ? exp(QK/32 - 4) : 0 (fp16), row partials -> atomicAdd L ----
__global__ __launch_bounds__(512, 2) void score_kernel(const short* __restrict__ Q,
                                                       const short* __restrict__ K,
                                                       const unsigned long long* __restrict__ Mbits,
                                                       short* __restrict__ S,
                                                       float* __restrict__ L) {
    extern __shared__ char smem[];
    int tid = threadIdx.x;
    int bid = blockIdx.x;
    int b = bid & 7, i = bid >> 3;          // batch -> XCD binding
    int n_t = i & 7, m_t = i >> 3;
    int tile_m = m_t * 256, tile_n = n_t * 256;
    const short* Aq = Q + (size_t)b * TQv * HD;
    const short* Bk = K + (size_t)b * TKv * HD;
    f32x4 acc[8][4] = {};
    gemm256_core<false>(Aq + (size_t)tile_m * HD, Bk + (size_t)tile_n * HD, HD, HD, smem, acc, tid);
    short* Sb = S + (size_t)b * TQv * TKv;
    const unsigned long long* Mb = Mbits + (size_t)b * TQv * (TKv / 64);
    float* Lb = L + (size_t)b * TQv;
    int wid = tid >> 6, lane = tid & 63;
    int wm = wid >> 2, wn = wid & 3;
    int l15 = lane & 15;
    int row0 = tile_m + wm * 128 + ((lane >> 4) << 2);
    int col0 = tile_n + wn * 64 + l15;
    int word = (tile_n + wn * 64) >> 6;
#pragma unroll
    for (int m = 0; m < 8; ++m)
#pragma unroll
        for (int r = 0; r < 4; ++r) {
            int gm = row0 + m * 16 + r;
            unsigned long long bits = Mb[(size_t)gm * (TKv / 64) + word];
            float rs = 0.f;
#pragma unroll
            for (int n = 0; n < 4; ++n) {
                float s = acc[m][n][r] * 0.03125f;
                float pv = ((bits >> (n * 16 + l15)) & 1ULL)
                               ? exp2f((s - 4.0f) * 1.44269504f) : 0.f;
                rs += pv;
                union { _Float16 h; short sh; } cv;
                cv.h = (_Float16)pv;
                Sb[(size_t)gm * TKv + col0 + n * 16] = cv.sh;
            }
            for (int sh = 1; sh < 16; sh <<= 1) rs += __shfl_xor(rs, sh);
            if (l15 == 0) atomicAdd(&Lb[gm], rs);
        }
}

// ---- pv: O = (P' . Vt^T) / L, fp16 MFMA, fp32 out ----
__global__ __launch_bounds__(512, 2) void pv_kernel(const short* __restrict__ P,
                                                    const short* __restrict__ Vt,
                                                    const float* __restrict__ L,
                                                    float* __restrict__ Out) {
    extern __shared__ char smem[];
    int tid = threadIdx.x;
    int bid = blockIdx.x;
    int b = bid & 7, i = bid >> 3;          // batch -> XCD binding
    int n_t = i & 3, m_t = i >> 2;          // n over HD (4), m over TQv (8)
    int tile_m = m_t * 256, tile_n = n_t * 256;
    const short* Ap = P + (size_t)b * TQv * TKv;
    const short* Bv = Vt + (size_t)b * HD * TKv;
    const float* Lb = L + (size_t)b * TQv;
    f32x4 acc[8][4] = {};
    gemm256_core<true>(Ap + (size_t)tile_m * TKv, Bv + (size_t)tile_n * TKv, TKv, TKv, smem, acc, tid);
    float* Ob = Out + (size_t)b * TQv * HD;
    int wid = tid >> 6, lane = tid & 63;
    int wm = wid >> 2, wn = wid & 3;
    int row0 = tile_m + wm * 128 + ((lane >> 4) << 2);
    int col0 = tile_n + wn * 64 + (lane & 15);
#pragma unroll
    for (int m = 0; m < 8; ++m)
#pragma unroll
        for (int r = 0; r < 4; ++r) {
            int gm = row0 + m * 16 + r;
            float l = Lb[gm];
            float inv = (l > 0.f) ? 1.f / l : 0.f;
#pragma unroll
            for (int n = 0; n < 4; ++n)
                Ob[(size_t)gm * HD + col0 + n * 16] = acc[m][n][r] * inv;
        }
}

extern "C" void kernel_launch(void* const* d_in, const int* in_sizes, int n_in,
                              void* d_out, int out_size, void* d_ws, size_t ws_size,
                              hipStream_t stream) {
    const float* query = (const float*)d_in[0];
    const float* enc   = (const float*)d_in[1];
    const int*   mask  = (const int*)d_in[2];
    const float* Wq    = (const float*)d_in[3];
    const float* bq    = (const float*)d_in[4];
    const float* Wk    = (const float*)d_in[5];
    const float* bk    = (const float*)d_in[6];
    const float* Wv    = (const float*)d_in[7];
    const float* bv    = (const float*)d_in[8];
    float* out = (float*)d_out;

    // workspace layout (bytes); total 174,063,616
    //   [0, 6.29MB): Wtq/Wtk/Wtv bf16 (wtrans -> projqk/projv), then reused as
    //     Mbits [0,4MB) + L [4MB,4MB+64KB) once the Wt copies are dead.
    //   S (fp16 P', 67MB) aliases Xq+Xe (dead after projqk/projv).
    char* ws = (char*)d_ws;
    short* Wt  = (short*)(ws);
    unsigned long long* Mbits = (unsigned long long*)(ws);
    float* L   = (float*)(ws + 4194304);
    short* Xq  = (short*)(ws + 6291456);
    short* Xe  = (short*)(ws + 39845888);
    short* S   = (short*)(ws + 6291456);       // aliases Xq,Xe
    short* Qb  = (short*)(ws + 73400320);
    short* Kb  = (short*)(ws + 106954752);
    short* Vt  = (short*)(ws + 140509184);
    (void)in_sizes; (void)n_in; (void)out_size; (void)ws_size;

    // 128 KiB dynamic LDS opt-in (one-time; not a stream op, graph-capture safe)
    static bool inited = false;
    if (!inited) {
        hipFuncSetAttribute((const void*)projqk_kernel, hipFuncAttributeMaxDynamicSharedMemorySize, 131072);
        hipFuncSetAttribute((const void*)projv_kernel,  hipFuncAttributeMaxDynamicSharedMemorySize, 131072);
        hipFuncSetAttribute((const void*)score_kernel,  hipFuncAttributeMaxDynamicSharedMemorySize, 131072);
        hipFuncSetAttribute((const void*)pv_kernel,     hipFuncAttributeMaxDynamicSharedMemorySize, 131072);
        inited = true;
    }

    convert_kernel<<<dim3(8192, 2), 256, 0, stream>>>(query, enc, Xq, Xe);
    wtrans_kernel<<<dim3(32, 32, 3), dim3(32, 8), 0, stream>>>(Wq, Wk, Wv, Wt);
    projqk_kernel<<<dim3(256, 1, 2), 512, 131072, stream>>>(Xq, Xe, Wt, bq, bk, Qb, Kb);
    projv_kernel<<<dim3(256), 512, 131072, stream>>>(Xe, Wt + (size_t)2 * HD * FD, bv, Vt);
    maskbits_kernel<<<dim3(2048), 256, 0, stream>>>(mask, Mbits, L);
    score_kernel<<<dim3(512), 512, 131072, stream>>>(Qb, Kb, Mbits, S, L);
    pv_kernel<<<dim3(256), 512, 131072, stream>>>(S, Vt, L, out);
}